// Round 1
// baseline (565.080 us; speedup 1.0000x reference)
//
#include <hip/hip_runtime.h>
#include <math.h>

// Problem constants (match reference)
constexpr int NR = 3200;
constexpr int NA = 320;
constexpr int TD = 512;
constexpr int DD = 128;
constexpr int H  = 128;
constexpr int B  = 8;

constexpr int ROWS_T = 4;
constexpr int ROWS_D = 8;
constexpr int NBLK_T = NR / ROWS_T;   // 800
constexpr int NBLK_D = NA / ROWS_D;   // 40

typedef float f4 __attribute__((ext_vector_type(4)));

// ---------------- prep: gemm_t | gemm_d | per-segment params -----------
// seg_res / seg_atom are SORTED (reference uses jnp.sort), so segment s is
// a contiguous rectangle [r0,r1) x [a0,a1). 8 params blocks compute the
// masked min/max distance^2 over their rectangle directly -> params[s].
// No Dbuf, no rowmin/rowmax, no segreduce launch.
__global__ __launch_bounds__(256) void prep_kernel(
    const float* __restrict__ At, const float* __restrict__ Wt, const float* __restrict__ bt,
    const float* __restrict__ Ad, const float* __restrict__ Wd, const float* __restrict__ bd,
    const float* __restrict__ tpos, const float* __restrict__ dpos,
    const int* __restrict__ seg_res, const int* __restrict__ seg_atom,
    float* __restrict__ tf, float* __restrict__ df, float2* __restrict__ params) {
    __shared__ float sA[ROWS_T * TD];   // 8 KB (fits ROWS_D*DD = 1024 too)
    __shared__ float sAcc[ROWS_D * H];  // 4 KB (also params reduce scratch)
    __shared__ int   sI[16];
    const int b = blockIdx.x;
    const int t = threadIdx.x;

    if (b < NBLK_T) {
        // ---- target GEMM: k-split halves across 256 threads ----
        const int h = t & (H - 1), half = t >> 7, i0 = b * ROWS_T;
        for (int idx = t; idx < ROWS_T * TD; idx += 256)
            sA[idx] = At[i0 * TD + idx];
        __syncthreads();
        float acc[ROWS_T];
#pragma unroll
        for (int r = 0; r < ROWS_T; r++) acc[r] = 0.0f;
        const int k0 = half * (TD / 2), k1 = k0 + (TD / 2);
#pragma unroll 4
        for (int k = k0; k < k1; k++) {
            const float w = Wt[k * H + h];
#pragma unroll
            for (int r = 0; r < ROWS_T; r++)
                acc[r] = fmaf(sA[r * TD + k], w, acc[r]);
        }
        if (half) {
#pragma unroll
            for (int r = 0; r < ROWS_T; r++) sAcc[r * H + h] = acc[r];
        }
        __syncthreads();
        if (!half) {
            const float bv = bt[h];
#pragma unroll
            for (int r = 0; r < ROWS_T; r++)
                tf[(i0 + r) * H + h] = acc[r] + sAcc[r * H + h] + bv;
        }
    } else if (b < NBLK_T + NBLK_D) {
        // ---- drug GEMM ----
        const int h = t & (H - 1), half = t >> 7, i0 = (b - NBLK_T) * ROWS_D;
        for (int idx = t; idx < ROWS_D * DD; idx += 256)
            sA[idx] = Ad[i0 * DD + idx];
        __syncthreads();
        float acc[ROWS_D];
#pragma unroll
        for (int r = 0; r < ROWS_D; r++) acc[r] = 0.0f;
        const int k0 = half * (DD / 2), k1 = k0 + (DD / 2);
#pragma unroll 4
        for (int k = k0; k < k1; k++) {
            const float w = Wd[k * H + h];
#pragma unroll
            for (int r = 0; r < ROWS_D; r++)
                acc[r] = fmaf(sA[r * DD + k], w, acc[r]);
        }
        if (half) {
#pragma unroll
            for (int r = 0; r < ROWS_D; r++) sAcc[r * H + h] = acc[r];
        }
        __syncthreads();
        if (!half) {
            const float bv = bd[h];
#pragma unroll
            for (int r = 0; r < ROWS_D; r++)
                df[(i0 + r) * H + h] = acc[r] + sAcc[r * H + h] + bv;
        }
    } else {
        // ---- params block s: segment range scan + masked min/max dist^2 ----
        const int s    = b - NBLK_T - NBLK_D;     // 0..7
        const int lane = t & 63, wid = t >> 6;
        // counts: r0 = #(seg_res < s), r1 = #(seg_res <= s); same for atoms
        int c0 = 0, c1 = 0, c2 = 0, c3 = 0;
        for (int r = t; r < NR; r += 256) {
            const int v = seg_res[r];
            c0 += (v < s); c1 += (v <= s);
        }
        for (int a = t; a < NA; a += 256) {
            const int v = seg_atom[a];
            c2 += (v < s); c3 += (v <= s);
        }
#pragma unroll
        for (int off = 32; off > 0; off >>= 1) {
            c0 += __shfl_down(c0, off); c1 += __shfl_down(c1, off);
            c2 += __shfl_down(c2, off); c3 += __shfl_down(c3, off);
        }
        if (lane == 0) { sI[wid] = c0; sI[4 + wid] = c1; sI[8 + wid] = c2; sI[12 + wid] = c3; }
        __syncthreads();
        const int r0 = sI[0] + sI[1] + sI[2] + sI[3];
        const int r1 = sI[4] + sI[5] + sI[6] + sI[7];
        const int a0 = sI[8] + sI[9] + sI[10] + sI[11];
        const int a1 = sI[12] + sI[13] + sI[14] + sI[15];
        // masked min/max over distance^2 (sqrt is monotone -> defer it)
        float mn = INFINITY, mx = -INFINITY;
        for (int i = r0 + wid; i < r1; i += 4) {
            const float tx = tpos[3 * i], ty = tpos[3 * i + 1], tz = tpos[3 * i + 2];
            for (int j = a0 + lane; j < a1; j += 64) {
                const float dx = tx - dpos[3 * j];
                const float dy = ty - dpos[3 * j + 1];
                const float dz = tz - dpos[3 * j + 2];
                const float d2 = fmaf(dx, dx, fmaf(dy, dy, dz * dz));
                mn = fminf(mn, d2);
                mx = fmaxf(mx, d2);
            }
        }
#pragma unroll
        for (int off = 32; off > 0; off >>= 1) {
            mn = fminf(mn, __shfl_down(mn, off));
            mx = fmaxf(mx, __shfl_down(mx, off));
        }
        __syncthreads();  // sI reads done before sAcc reuse
        if (lane == 0) { sAcc[wid] = mn; sAcc[4 + wid] = mx; }
        __syncthreads();
        if (t == 0) {
            const float m2 = fminf(fminf(sAcc[0], sAcc[1]), fminf(sAcc[2], sAcc[3]));
            const float x2 = fmaxf(fmaxf(sAcc[4], sAcc[5]), fmaxf(sAcc[6], sAcc[7]));
            const float dmin  = (m2 < INFINITY)  ? sqrtf(m2) : 0.0f;
            const float dmax  = (x2 > -INFINITY) ? sqrtf(x2) : 1.0f;
            const float denom = (dmax > dmin) ? (dmax - dmin) : 1.0f;
            params[s] = make_float2(dmin, 1.0f / denom);
        }
    }
}

// ---------------- fast tanh --------------------------------------------
__device__ __forceinline__ float fast_tanh(float x) {
    const float cx = fminf(fmaxf(x, -15.0f), 15.0f);
    const float e  = __expf(2.0f * cx);
    return 1.0f - __fdividef(2.0f, e + 1.0f);
}

// ---------------- the 524 MB writer -------------------------------------
// grid = (40, NR): blockIdx.y = residue i, so seg_res[i] / tpos[i] are
// block-uniform scalars. Distance recomputed inline (~9 VALU ops/thread,
// invisible under a 16 B/thread NT store) — no Dbuf round-trip.
__global__ __launch_bounds__(256) void final_kernel(
    const float* __restrict__ tf, const float* __restrict__ df,
    const float* __restrict__ tpos, const float* __restrict__ dpos,
    const int* __restrict__ seg_res, const int* __restrict__ seg_atom,
    const float2* __restrict__ params, float* __restrict__ out) {
    const int i = blockIdx.y;
    const int e = (blockIdx.x * 256 + threadIdx.x) * 4;  // 0..40959 within row
    const int j = e >> 7;
    const int h = e & 127;

    f4 o = {0.0f, 0.0f, 0.0f, 0.0f};
    const int sr = seg_res[i];
    if (seg_atom[j] == sr) {
        const float2 pp = params[sr];
        const float dx = tpos[3 * i]     - dpos[3 * j];
        const float dy = tpos[3 * i + 1] - dpos[3 * j + 1];
        const float dz = tpos[3 * i + 2] - dpos[3 * j + 2];
        const float d  = sqrtf(fmaf(dx, dx, fmaf(dy, dy, dz * dz)));
        const float dn = (d - pp.x) * pp.y;
        const f4 tv = *(const f4*)(tf + i * H + h);
        const f4 dv = *(const f4*)(df + j * H + h);
        o.x = fast_tanh(tv.x - dv.x + dn);
        o.y = fast_tanh(tv.y - dv.y + dn);
        o.z = fast_tanh(tv.z - dv.z + dn);
        o.w = fast_tanh(tv.w - dv.w + dn);
    }
    __builtin_nontemporal_store(o, (f4*)(out + (long long)i * (NA * H) + e));
}

extern "C" void kernel_launch(void* const* d_in, const int* in_sizes, int n_in,
                              void* d_out, int out_size, void* d_ws, size_t ws_size,
                              hipStream_t stream) {
    const float* target_feature = (const float*)d_in[0];  // [NR, TD]
    const float* drug_feature   = (const float*)d_in[1];  // [NA, DD]
    const float* target_pos     = (const float*)d_in[2];  // [NR, 3]
    const float* drug_pos       = (const float*)d_in[3];  // [NA, 3]
    const float* Wt             = (const float*)d_in[4];  // [TD, H]
    const float* bt             = (const float*)d_in[5];  // [H]
    const float* Wd             = (const float*)d_in[6];  // [DD, H]
    const float* bd             = (const float*)d_in[7];  // [H]
    const int*   seg_res        = (const int*)d_in[8];    // [NR]
    const int*   seg_atom       = (const int*)d_in[9];    // [NA]
    float* out = (float*)d_out;

    // workspace (floats): tf | df | params
    float*  ws     = (float*)d_ws;
    float*  tf     = ws;                       // NR*H = 409,600
    float*  df     = tf + NR * H;              // NA*H =  40,960
    float2* params = (float2*)(df + NA * H);   // B

    prep_kernel<<<NBLK_T + NBLK_D + B, 256, 0, stream>>>(
        target_feature, Wt, bt, drug_feature, Wd, bd,
        target_pos, drug_pos, seg_res, seg_atom, tf, df, params);
    final_kernel<<<dim3(NA * H / (4 * 256), NR), 256, 0, stream>>>(
        tf, df, target_pos, drug_pos, seg_res, seg_atom, params, out);
}